// Round 4
// baseline (2502.625 us; speedup 1.0000x reference)
//
#include <hip/hip_runtime.h>

// LightGCN, col-tiled CSR + L2-resident gathers.
// Pipeline: memset(cnt2,counter) -> k_count2 (2 atomics/edge, per-(row,tile)
//   tickets) -> k_rowoffs (per-row scan of T tile counts + block scan of row
//   sums) -> k_scatter2 (atomic-free) -> k_dinv -> k_init (g0=bf16(dinv*e0))
//   -> 4x k_layer_tiled (tile-phased gathers, acc in VGPRs) -> k_final.
//
// g-form: g = dinv(*)e; s_r = sum v*g_c; e'_r = dinv_r*s_r; g' = dinv_r*e'_r.
// k_final reconstructs acc = e0 + sum_l dsq*g_l (dsq = sqrt(deg)).
//
// Tiling: tile(col) = col >> 14 (2MB bf16 working set per tile <= 4MB per-XCD
// L2). CSR entries grouped per (row,tile); offs2[row*(T+1)+t] bounds each
// segment, segments of a row contiguous. Layer kernel: wave owns 40 rows,
// loops tiles; all blocks co-resident (938 <= 1024 @ launch_bounds(256,4))
// so waves stay tile-aligned without any grid sync.

#define TILE_SHIFT 14
#define ROWS_PER_WAVE 40

static inline size_t align_up(size_t x, size_t a) { return (x + a - 1) & ~(a - 1); }

__device__ inline unsigned short f32_to_bf16(float f) {
    unsigned int u = __float_as_uint(f);
    unsigned int r = (u + 0x7FFFu + ((u >> 16) & 1u)) >> 16;   // RNE
    return (unsigned short)r;
}
__device__ inline float bf16_to_f32(unsigned short h) {
    return __uint_as_float(((unsigned int)h) << 16);
}

// 2 atomics/edge into per-(row,tile) counters; ticket = slot within segment.
__global__ void k_count2(const int* __restrict__ eu, const int* __restrict__ ei,
                         int* __restrict__ cnt2,
                         int* __restrict__ tick_u, int* __restrict__ tick_i,
                         int U, int E, int T) {
    int e = blockIdx.x * blockDim.x + threadIdx.x;
    if (e >= E) return;
    int u = eu[e];
    int it = ei[e] + U;
    // user row u gathers col=it; item row it gathers col=u
    tick_u[e] = atomicAdd(&cnt2[(size_t)u * T + (it >> TILE_SHIFT)], 1);
    tick_i[e] = atomicAdd(&cnt2[(size_t)it * T + (u >> TILE_SHIFT)], 1);
}

// Per-row: sum T tile counts, local prefix; block scan of row sums + one
// global atomic for base. Writes offs2[row*(T+1)+0..T] (incl. sentinel) and
// rowcnt. Row order across blocks is arbitrary (only per-row contiguity used).
__global__ __launch_bounds__(256) void k_rowoffs(
        const int* __restrict__ cnt2, int* __restrict__ offs2,
        int* __restrict__ rowcnt, int* __restrict__ counter, int N, int T) {
    __shared__ int sdata[256];
    __shared__ int sbase;
    int t = threadIdx.x;
    int n = blockIdx.x * 256 + t;
    int pre[16];   // T <= 16 assumed (T=10 here)
    int rc = 0;
    if (n < N) {
        for (int k = 0; k < T; ++k) {
            pre[k] = rc;
            rc += cnt2[(size_t)n * T + k];
        }
    }
    sdata[t] = rc;
    __syncthreads();
    for (int d = 1; d < 256; d <<= 1) {
        int v = (t >= d) ? sdata[t - d] : 0;
        __syncthreads();
        sdata[t] += v;
        __syncthreads();
    }
    if (t == 255) sbase = atomicAdd(counter, sdata[255]);
    __syncthreads();
    if (n < N) {
        int start = sbase + sdata[t] - rc;
        size_t b = (size_t)n * (T + 1);
        for (int k = 0; k < T; ++k) offs2[b + k] = start + pre[k];
        offs2[b + T] = start + rc;
        rowcnt[n] = rc;
    }
}

// Atomic-free scatter into tiled slots. Stores {col, raw v}.
__global__ void k_scatter2(const int* __restrict__ eu, const int* __restrict__ ei,
                           const float* __restrict__ ev,
                           const int* __restrict__ offs2,
                           const int* __restrict__ tick_u, const int* __restrict__ tick_i,
                           int2* __restrict__ csr, int U, int E, int T) {
    int e = blockIdx.x * blockDim.x + threadIdx.x;
    if (e >= E) return;
    int u = eu[e];
    int it = ei[e] + U;
    int vy = __float_as_int(ev[e]);
    int2 a;
    a.x = it; a.y = vy;
    csr[offs2[(size_t)u * (T + 1) + (it >> TILE_SHIFT)] + tick_u[e]] = a;
    a.x = u;
    csr[offs2[(size_t)it * (T + 1) + (u >> TILE_SHIFT)] + tick_i[e]] = a;
}

// One wave per row: deg = sum v over the row's (contiguous) entries.
__global__ __launch_bounds__(256) void k_dinv(
        const int2* __restrict__ csr, const int* __restrict__ offs2,
        const int* __restrict__ rowcnt, float* __restrict__ dinv,
        float* __restrict__ dsq, int N, int T) {
    int gtid = blockIdx.x * blockDim.x + threadIdx.x;
    int wid = gtid >> 6;
    int lane = threadIdx.x & 63;
    if (wid >= N) return;
    int base = offs2[(size_t)wid * (T + 1)];
    int c = rowcnt[wid];
    float s = 0.f;
    for (int k = lane; k < c; k += 64) s += __int_as_float(csr[base + k].y);
    #pragma unroll
    for (int d = 32; d > 0; d >>= 1) s += __shfl_down(s, d);
    if (lane == 0) {
        bool pos = (s > 0.0f);
        dinv[wid] = pos ? rsqrtf(fmaxf(s, 1e-12f)) : 0.0f;
        dsq[wid]  = pos ? sqrtf(s) : 0.0f;
    }
}

// g0 = bf16(dinv * concat(emb)). 4 elems/thread.
__global__ void k_init(const float4* __restrict__ emb_u, const float4* __restrict__ emb_i,
                       const float* __restrict__ dinv,
                       ushort4* __restrict__ g0, int U16, int N16) {
    int i = blockIdx.x * blockDim.x + threadIdx.x;
    if (i >= N16) return;
    float4 v = (i < U16) ? emb_u[i] : emb_i[i - U16];
    float d = dinv[i >> 4];
    ushort4 o;
    o.x = f32_to_bf16(v.x * d);
    o.y = f32_to_bf16(v.y * d);
    o.z = f32_to_bf16(v.z * d);
    o.w = f32_to_bf16(v.w * d);
    g0[i] = o;
}

// Tile-phased layer. Wave owns ROWS_PER_WAVE consecutive rows; acc[40] in
// VGPRs; tiles looped outermost so concurrent waves gather from the same
// ~2MB col region (per-XCD L2 resident). Rows processed 4 at a time for MLP.
__global__ __launch_bounds__(256, 4) void k_layer_tiled(
        const unsigned short* __restrict__ gin, unsigned short* __restrict__ gout,
        const float* __restrict__ dinv,
        const int* __restrict__ offs2, const int2* __restrict__ csr,
        int N, int T) {
    int gtid = blockIdx.x * blockDim.x + threadIdx.x;
    int wave = gtid >> 6;
    int lane = threadIdx.x & 63;
    int wbase = wave * ROWS_PER_WAVE;
    if (wbase >= N) return;
    int T1 = T + 1;

    float acc[ROWS_PER_WAVE];
    #pragma unroll
    for (int r = 0; r < ROWS_PER_WAVE; ++r) acc[r] = 0.f;

    for (int t = 0; t < T; ++t) {
        // meta gather: lanes hold offs2[(wbase+q)*T1 + t + {0,1}]
        // m0: rows 0..31 (lanes 0..63), m1: rows 32..39 (lanes 0..15)
        int q0 = lane >> 1;
        int r0c = min(wbase + q0, N - 1);
        int m0 = offs2[(size_t)r0c * T1 + t + (lane & 1)];
        int q1 = 32 + (lane >> 1);
        int r1c = min(wbase + (q1 < ROWS_PER_WAVE ? q1 : 0), N - 1);
        int m1 = offs2[(size_t)r1c * T1 + t + (lane & 1)];

        #pragma unroll
        for (int grp = 0; grp < ROWS_PER_WAVE / 4; ++grp) {
            int s0, e0, s1, e1, s2, e2, s3, e3;
            if (grp < 8) {
                int b = grp * 8;
                s0 = __builtin_amdgcn_readlane(m0, b + 0); e0 = __builtin_amdgcn_readlane(m0, b + 1);
                s1 = __builtin_amdgcn_readlane(m0, b + 2); e1 = __builtin_amdgcn_readlane(m0, b + 3);
                s2 = __builtin_amdgcn_readlane(m0, b + 4); e2 = __builtin_amdgcn_readlane(m0, b + 5);
                s3 = __builtin_amdgcn_readlane(m0, b + 6); e3 = __builtin_amdgcn_readlane(m0, b + 7);
            } else {
                int b = (grp - 8) * 8;
                s0 = __builtin_amdgcn_readlane(m1, b + 0); e0 = __builtin_amdgcn_readlane(m1, b + 1);
                s1 = __builtin_amdgcn_readlane(m1, b + 2); e1 = __builtin_amdgcn_readlane(m1, b + 3);
                s2 = __builtin_amdgcn_readlane(m1, b + 4); e2 = __builtin_amdgcn_readlane(m1, b + 5);
                s3 = __builtin_amdgcn_readlane(m1, b + 6); e3 = __builtin_amdgcn_readlane(m1, b + 7);
            }
            int rowg = wbase + grp * 4;
            int c0 = (rowg + 0 < N) ? e0 - s0 : 0;
            int c1 = (rowg + 1 < N) ? e1 - s1 : 0;
            int c2 = (rowg + 2 < N) ? e2 - s2 : 0;
            int c3 = (rowg + 3 < N) ? e3 - s3 : 0;
            int maxc = max(max(c0, c1), max(c2, c3));
            for (int b = 0; b < maxc; b += 64) {
                int2 cw0 = make_int2(0, 0), cw1 = make_int2(0, 0);
                int2 cw2 = make_int2(0, 0), cw3 = make_int2(0, 0);
                int idx = b + lane;
                if (idx < c0) cw0 = csr[s0 + idx];
                if (idx < c1) cw1 = csr[s1 + idx];
                if (idx < c2) cw2 = csr[s2 + idx];
                if (idx < c3) cw3 = csr[s3 + idx];
                int mm = min(maxc - b, 64);
                for (int j = 0; j < mm; ++j) {
                    if (j < c0 - b) {
                        int col = __builtin_amdgcn_readlane(cw0.x, j);
                        float w = __int_as_float(__builtin_amdgcn_readlane(cw0.y, j));
                        acc[grp * 4 + 0] += w * bf16_to_f32(gin[(size_t)col * 64 + lane]);
                    }
                    if (j < c1 - b) {
                        int col = __builtin_amdgcn_readlane(cw1.x, j);
                        float w = __int_as_float(__builtin_amdgcn_readlane(cw1.y, j));
                        acc[grp * 4 + 1] += w * bf16_to_f32(gin[(size_t)col * 64 + lane]);
                    }
                    if (j < c2 - b) {
                        int col = __builtin_amdgcn_readlane(cw2.x, j);
                        float w = __int_as_float(__builtin_amdgcn_readlane(cw2.y, j));
                        acc[grp * 4 + 2] += w * bf16_to_f32(gin[(size_t)col * 64 + lane]);
                    }
                    if (j < c3 - b) {
                        int col = __builtin_amdgcn_readlane(cw3.x, j);
                        float w = __int_as_float(__builtin_amdgcn_readlane(cw3.y, j));
                        acc[grp * 4 + 3] += w * bf16_to_f32(gin[(size_t)col * 64 + lane]);
                    }
                }
            }
        }
    }

    // write-out: g' = dinv^2 * s for owned rows
    #pragma unroll
    for (int r = 0; r < ROWS_PER_WAVE; ++r) {
        int row = wbase + r;
        if (row < N) {
            float dr = dinv[row];
            gout[(size_t)row * 64 + lane] = f32_to_bf16(dr * dr * acc[r]);
        }
    }
}

// out (float4 units): [Uf | Upass | If | Ipass]; Uf/If = (e0 + sum dsq*g_l)/25.
__global__ void k_final(const float4* __restrict__ emb_u, const float4* __restrict__ emb_i,
                        const ushort4* __restrict__ g1, const ushort4* __restrict__ g2,
                        const ushort4* __restrict__ g3, const ushort4* __restrict__ g4,
                        const float* __restrict__ dsq,
                        float4* __restrict__ out, int U16, int I16) {
    int i = blockIdx.x * blockDim.x + threadIdx.x;
    int total = 2 * U16 + 2 * I16;
    if (i >= total) return;
    const float s = 1.0f / 25.0f;
    float4 r;
    if (i < U16 || (i >= 2 * U16 && i < 2 * U16 + I16)) {
        int gi, node;
        float4 e0;
        if (i < U16) { gi = i; node = i >> 4; e0 = emb_u[i]; }
        else { int j = i - 2 * U16; gi = U16 + j; node = (U16 >> 4) + (j >> 4); e0 = emb_i[j]; }
        float d = dsq[node];
        ushort4 a = g1[gi], b = g2[gi], cc = g3[gi], dd = g4[gi];
        float gx = bf16_to_f32(a.x) + bf16_to_f32(b.x) + bf16_to_f32(cc.x) + bf16_to_f32(dd.x);
        float gy = bf16_to_f32(a.y) + bf16_to_f32(b.y) + bf16_to_f32(cc.y) + bf16_to_f32(dd.y);
        float gz = bf16_to_f32(a.z) + bf16_to_f32(b.z) + bf16_to_f32(cc.z) + bf16_to_f32(dd.z);
        float gw = bf16_to_f32(a.w) + bf16_to_f32(b.w) + bf16_to_f32(cc.w) + bf16_to_f32(dd.w);
        r = make_float4((e0.x + d * gx) * s, (e0.y + d * gy) * s,
                        (e0.z + d * gz) * s, (e0.w + d * gw) * s);
    } else if (i < 2 * U16) {
        r = emb_u[i - U16];
    } else {
        r = emb_i[i - 2 * U16 - I16];
    }
    out[i] = r;
}

extern "C" void kernel_launch(void* const* d_in, const int* in_sizes, int n_in,
                              void* d_out, int out_size, void* d_ws, size_t ws_size,
                              hipStream_t stream) {
    const float* emb_u = (const float*)d_in[0];
    const float* emb_i = (const float*)d_in[1];
    const int*   eu    = (const int*)d_in[2];
    const int*   ei    = (const int*)d_in[3];
    const float* ev    = (const float*)d_in[4];

    const int U = in_sizes[0] / 64;
    const int I = in_sizes[1] / 64;
    const int N = U + I;
    const int E = in_sizes[2];
    const int DE = 2 * E;
    const int T = (N + (1 << TILE_SHIFT) - 1) >> TILE_SHIFT;   // 10 for N=150000

    // ---- workspace carve (cnt2+counter first: one memset) ----
    char* base = (char*)d_ws;
    size_t off = 0;
    int*   cnt2    = (int*)(base + off); off = align_up(off + (size_t)N * T * 4, 256);
    int*   counter = (int*)(base + off); off = align_up(off + 256, 256);
    size_t zero_span = off;
    int*   offs2  = (int*)  (base + off); off = align_up(off + (size_t)N * (T + 1) * 4, 256);
    int*   rowcnt = (int*)  (base + off); off = align_up(off + (size_t)N * 4, 256);
    float* dinv   = (float*)(base + off); off = align_up(off + (size_t)N * 4, 256);
    float* dsq    = (float*)(base + off); off = align_up(off + (size_t)N * 4, 256);
    int*   tick_u = (int*)  (base + off); off = align_up(off + (size_t)E * 4, 256);
    int*   tick_i = (int*)  (base + off); off = align_up(off + (size_t)E * 4, 256);
    int2*  csr    = (int2*) (base + off); off = align_up(off + (size_t)DE * 8, 256);
    unsigned short* g[5];
    for (int l = 0; l < 5; ++l) {
        g[l] = (unsigned short*)(base + off);
        off = align_up(off + (size_t)N * 64 * 2, 256);
    }
    (void)ws_size;

    hipMemsetAsync(d_ws, 0, zero_span, stream);

    const int B = 256;
    k_count2<<<(E + B - 1) / B, B, 0, stream>>>(eu, ei, cnt2, tick_u, tick_i, U, E, T);
    k_rowoffs<<<(N + B - 1) / B, B, 0, stream>>>(cnt2, offs2, rowcnt, counter, N, T);
    k_scatter2<<<(E + B - 1) / B, B, 0, stream>>>(eu, ei, ev, offs2, tick_u, tick_i, csr, U, E, T);
    k_dinv<<<(N * 64 + B - 1) / B, B, 0, stream>>>(csr, offs2, rowcnt, dinv, dsq, N, T);

    const int U16 = U * 16, I16 = I * 16, N16 = N * 16;
    k_init<<<(N16 + B - 1) / B, B, 0, stream>>>((const float4*)emb_u, (const float4*)emb_i,
                                                dinv, (ushort4*)g[0], U16, N16);

    const int ROWS_PER_BLOCK = 4 * ROWS_PER_WAVE;   // 4 waves/block
    int lblocks = (N + ROWS_PER_BLOCK - 1) / ROWS_PER_BLOCK;  // 938 for N=150000
    for (int layer = 0; layer < 4; ++layer) {
        k_layer_tiled<<<lblocks, B, 0, stream>>>(g[layer], g[layer + 1], dinv,
                                                 offs2, csr, N, T);
    }

    int totalv4 = 2 * U16 + 2 * I16;
    k_final<<<(totalv4 + B - 1) / B, B, 0, stream>>>(
        (const float4*)emb_u, (const float4*)emb_i,
        (const ushort4*)g[1], (const ushort4*)g[2], (const ushort4*)g[3], (const ushort4*)g[4],
        dsq, (float4*)d_out, U16, I16);
}

// Round 5
// 772.456 us; speedup vs baseline: 3.2398x; 3.2398x over previous
//
#include <hip/hip_runtime.h>

// LightGCN, atomic-minimized + bf16 g-form + 4-neighbors-per-load layer.
// Pipeline: memset(cnt,counter) -> k_count (2 atomics/edge, tickets)
//   -> k_offsets (block scan) -> k_scatter (atomic-free) -> k_dinv
//   -> k_init (g0 = bf16(dinv*e0)) -> 4x k_layer -> k_final.
//
// g-form: g = dinv(*)e; s_r = sum v*g_c; e'_r = dinv_r*s_r; g' = dinv_r*e'_r.
// k_final reconstructs acc = e0 + sum_l dsq*g_l (dsq = sqrt(deg)).
//
// k_layer lane layout: nb = lane>>4 (neighbor subgroup 0..3), q = lane&15
// (dim quad, ushort4 = 4 bf16 dims). One 8B load/lane covers 4 neighbor rows
// (4 x 128B lines) -> 2 shfl-broadcasts per 4 neighbors (vs 8 in the R3
// per-dim layout). Cross-subgroup reduce: shfl_xor 16,32 at row end only.

static inline size_t align_up(size_t x, size_t a) { return (x + a - 1) & ~(a - 1); }

__device__ inline unsigned short f32_to_bf16(float f) {
    unsigned int u = __float_as_uint(f);
    unsigned int r = (u + 0x7FFFu + ((u >> 16) & 1u)) >> 16;   // RNE
    return (unsigned short)r;
}
__device__ inline float bf16_to_f32(unsigned short h) {
    return __uint_as_float(((unsigned int)h) << 16);
}

// 2 atomics/edge; ticket (returned old count) = slot within the row.
__global__ void k_count(const int* __restrict__ eu, const int* __restrict__ ei,
                        int* __restrict__ cnt,
                        int* __restrict__ tick_u, int* __restrict__ tick_i,
                        int U, int E) {
    int e = blockIdx.x * blockDim.x + threadIdx.x;
    if (e >= E) return;
    int u = eu[e];
    int it = ei[e] + U;
    tick_u[e] = atomicAdd(&cnt[u], 1);
    tick_i[e] = atomicAdd(&cnt[it], 1);
}

// Block scan + one global atomic per block -> disjoint CSR ranges.
__global__ __launch_bounds__(256) void k_offsets(
        const int* __restrict__ cnt, int* __restrict__ offs,
        int* __restrict__ counter, int N) {
    __shared__ int sdata[256];
    __shared__ int sbase;
    int t = threadIdx.x;
    int n = blockIdx.x * 256 + t;
    int c = (n < N) ? cnt[n] : 0;
    sdata[t] = c;
    __syncthreads();
    for (int d = 1; d < 256; d <<= 1) {
        int v = (t >= d) ? sdata[t - d] : 0;
        __syncthreads();
        sdata[t] += v;
        __syncthreads();
    }
    if (t == 255) sbase = atomicAdd(counter, sdata[255]);
    __syncthreads();
    if (n < N) offs[n] = sbase + sdata[t] - c;
}

// Atomic-free scatter: slot = offs[node] + ticket. Stores {col, raw v}.
__global__ void k_scatter(const int* __restrict__ eu, const int* __restrict__ ei,
                          const float* __restrict__ ev,
                          const int* __restrict__ offs,
                          const int* __restrict__ tick_u, const int* __restrict__ tick_i,
                          int2* __restrict__ csr, int U, int E) {
    int e = blockIdx.x * blockDim.x + threadIdx.x;
    if (e >= E) return;
    int u = eu[e];
    int it = ei[e] + U;
    int vy = __float_as_int(ev[e]);
    int2 a;
    a.x = it; a.y = vy;
    csr[offs[u] + tick_u[e]] = a;
    a.x = u;
    csr[offs[it] + tick_i[e]] = a;
}

// One wave per row: deg = sum v over CSR row; dinv = rsqrt(deg), dsq = sqrt(deg).
__global__ __launch_bounds__(256) void k_dinv(
        const int2* __restrict__ csr, const int* __restrict__ offs,
        const int* __restrict__ cnt, float* __restrict__ dinv,
        float* __restrict__ dsq, int N) {
    int gtid = blockIdx.x * blockDim.x + threadIdx.x;
    int wid = gtid >> 6;
    int lane = threadIdx.x & 63;
    if (wid >= N) return;
    int base = offs[wid];
    int c = cnt[wid];
    float s = 0.f;
    for (int k = lane; k < c; k += 64) s += __int_as_float(csr[base + k].y);
    #pragma unroll
    for (int d = 32; d > 0; d >>= 1) s += __shfl_down(s, d);
    if (lane == 0) {
        bool pos = (s > 0.0f);
        dinv[wid] = pos ? rsqrtf(fmaxf(s, 1e-12f)) : 0.0f;
        dsq[wid]  = pos ? sqrtf(s) : 0.0f;
    }
}

// g0 = bf16(dinv * concat(emb)). 4 elems/thread.
__global__ void k_init(const float4* __restrict__ emb_u, const float4* __restrict__ emb_i,
                       const float* __restrict__ dinv,
                       ushort4* __restrict__ g0, int U16, int N16) {
    int i = blockIdx.x * blockDim.x + threadIdx.x;
    if (i >= N16) return;
    float4 v = (i < U16) ? emb_u[i] : emb_i[i - U16];
    float d = dinv[i >> 4];
    ushort4 o;
    o.x = f32_to_bf16(v.x * d);
    o.y = f32_to_bf16(v.y * d);
    o.z = f32_to_bf16(v.z * d);
    o.w = f32_to_bf16(v.w * d);
    g0[i] = o;
}

// One wave per row. See header comment for lane layout.
__global__ __launch_bounds__(256) void k_layer(
        const ushort4* __restrict__ gin, ushort4* __restrict__ gout,
        const float* __restrict__ dinv,
        const int* __restrict__ offs, const int* __restrict__ cnt,
        const int2* __restrict__ csr, int N) {
    int gtid = blockIdx.x * blockDim.x + threadIdx.x;
    int row = gtid >> 6;
    int lane = threadIdx.x & 63;
    if (row >= N) return;
    int nb = lane >> 4;      // neighbor subgroup 0..3
    int q  = lane & 15;      // dim quad
    int base = offs[row];
    int c = cnt[row];

    float ax = 0.f, ay = 0.f, az = 0.f, aw = 0.f;

    for (int k0 = 0; k0 < c; k0 += 64) {
        int idx = k0 + lane;
        int2 cw = make_int2(0, 0);
        if (idx < c) cw = csr[base + idx];   // lanes >= m hold {0, 0.0f}
        int m = min(c - k0, 64);
        int j = 0;
        // 8 neighbors (2 subgroup-steps) per iteration; independent loads.
        for (; j + 8 <= m; j += 8) {
            int   colA = __shfl(cw.x, j + nb);
            float wA   = __int_as_float(__shfl(cw.y, j + nb));
            int   colB = __shfl(cw.x, j + 4 + nb);
            float wB   = __int_as_float(__shfl(cw.y, j + 4 + nb));
            ushort4 gA = gin[(size_t)colA * 16 + q];
            ushort4 gB = gin[(size_t)colB * 16 + q];
            ax += wA * bf16_to_f32(gA.x);
            ay += wA * bf16_to_f32(gA.y);
            az += wA * bf16_to_f32(gA.z);
            aw += wA * bf16_to_f32(gA.w);
            ax += wB * bf16_to_f32(gB.x);
            ay += wB * bf16_to_f32(gB.y);
            az += wB * bf16_to_f32(gB.z);
            aw += wB * bf16_to_f32(gB.w);
        }
        for (; j < m; j += 4) {
            // tail: lanes with j+nb >= m read cw=(0,0) from padded lanes
            // (j+nb <= 63 always: last j = 4*floor((m-1)/4), nb <= 3)
            int   col = __shfl(cw.x, j + nb);
            float w   = __int_as_float(__shfl(cw.y, j + nb));
            ushort4 gv = gin[(size_t)col * 16 + q];
            ax += w * bf16_to_f32(gv.x);
            ay += w * bf16_to_f32(gv.y);
            az += w * bf16_to_f32(gv.z);
            aw += w * bf16_to_f32(gv.w);
        }
    }

    // reduce across the 4 neighbor subgroups (lanes xor 16, 32)
    ax += __shfl_xor(ax, 16); ay += __shfl_xor(ay, 16);
    az += __shfl_xor(az, 16); aw += __shfl_xor(aw, 16);
    ax += __shfl_xor(ax, 32); ay += __shfl_xor(ay, 32);
    az += __shfl_xor(az, 32); aw += __shfl_xor(aw, 32);

    if (nb == 0) {
        float dr = dinv[row];
        float d2 = dr * dr;
        ushort4 o;
        o.x = f32_to_bf16(d2 * ax);
        o.y = f32_to_bf16(d2 * ay);
        o.z = f32_to_bf16(d2 * az);
        o.w = f32_to_bf16(d2 * aw);
        gout[(size_t)row * 16 + q] = o;
    }
}

// out (float4 units): [Uf | Upass | If | Ipass]; Uf/If = (e0 + sum dsq*g_l)/25.
__global__ void k_final(const float4* __restrict__ emb_u, const float4* __restrict__ emb_i,
                        const ushort4* __restrict__ g1, const ushort4* __restrict__ g2,
                        const ushort4* __restrict__ g3, const ushort4* __restrict__ g4,
                        const float* __restrict__ dsq,
                        float4* __restrict__ out, int U16, int I16) {
    int i = blockIdx.x * blockDim.x + threadIdx.x;
    int total = 2 * U16 + 2 * I16;
    if (i >= total) return;
    const float s = 1.0f / 25.0f;
    float4 r;
    if (i < U16 || (i >= 2 * U16 && i < 2 * U16 + I16)) {
        int gi, node;
        float4 e0;
        if (i < U16) { gi = i; node = i >> 4; e0 = emb_u[i]; }
        else { int j = i - 2 * U16; gi = U16 + j; node = (U16 >> 4) + (j >> 4); e0 = emb_i[j]; }
        float d = dsq[node];
        ushort4 a = g1[gi], b = g2[gi], cc = g3[gi], dd = g4[gi];
        float gx = bf16_to_f32(a.x) + bf16_to_f32(b.x) + bf16_to_f32(cc.x) + bf16_to_f32(dd.x);
        float gy = bf16_to_f32(a.y) + bf16_to_f32(b.y) + bf16_to_f32(cc.y) + bf16_to_f32(dd.y);
        float gz = bf16_to_f32(a.z) + bf16_to_f32(b.z) + bf16_to_f32(cc.z) + bf16_to_f32(dd.z);
        float gw = bf16_to_f32(a.w) + bf16_to_f32(b.w) + bf16_to_f32(cc.w) + bf16_to_f32(dd.w);
        r = make_float4((e0.x + d * gx) * s, (e0.y + d * gy) * s,
                        (e0.z + d * gz) * s, (e0.w + d * gw) * s);
    } else if (i < 2 * U16) {
        r = emb_u[i - U16];
    } else {
        r = emb_i[i - 2 * U16 - I16];
    }
    out[i] = r;
}

extern "C" void kernel_launch(void* const* d_in, const int* in_sizes, int n_in,
                              void* d_out, int out_size, void* d_ws, size_t ws_size,
                              hipStream_t stream) {
    const float* emb_u = (const float*)d_in[0];
    const float* emb_i = (const float*)d_in[1];
    const int*   eu    = (const int*)d_in[2];
    const int*   ei    = (const int*)d_in[3];
    const float* ev    = (const float*)d_in[4];

    const int U = in_sizes[0] / 64;
    const int I = in_sizes[1] / 64;
    const int N = U + I;
    const int E = in_sizes[2];
    const int DE = 2 * E;

    // ---- workspace carve (cnt+counter first: single small memset) ----
    char* base = (char*)d_ws;
    size_t off = 0;
    int*   cnt     = (int*)(base + off); off = align_up(off + (size_t)N * 4, 256);
    int*   counter = (int*)(base + off); off = align_up(off + 256, 256);
    size_t zero_span = off;
    int*   offs   = (int*)  (base + off); off = align_up(off + (size_t)N * 4, 256);
    float* dinv   = (float*)(base + off); off = align_up(off + (size_t)N * 4, 256);
    float* dsq    = (float*)(base + off); off = align_up(off + (size_t)N * 4, 256);
    int*   tick_u = (int*)  (base + off); off = align_up(off + (size_t)E * 4, 256);
    int*   tick_i = (int*)  (base + off); off = align_up(off + (size_t)E * 4, 256);
    int2*  csr    = (int2*) (base + off); off = align_up(off + (size_t)DE * 8, 256);
    unsigned short* g[5];
    for (int l = 0; l < 5; ++l) {
        g[l] = (unsigned short*)(base + off);
        off = align_up(off + (size_t)N * 64 * 2, 256);
    }
    (void)ws_size;

    hipMemsetAsync(d_ws, 0, zero_span, stream);

    const int B = 256;
    k_count<<<(E + B - 1) / B, B, 0, stream>>>(eu, ei, cnt, tick_u, tick_i, U, E);
    k_offsets<<<(N + B - 1) / B, B, 0, stream>>>(cnt, offs, counter, N);
    k_scatter<<<(E + B - 1) / B, B, 0, stream>>>(eu, ei, ev, offs, tick_u, tick_i, csr, U, E);
    k_dinv<<<(N * 64 + B - 1) / B, B, 0, stream>>>(csr, offs, cnt, dinv, dsq, N);

    const int U16 = U * 16, I16 = I * 16, N16 = N * 16;
    k_init<<<(N16 + B - 1) / B, B, 0, stream>>>((const float4*)emb_u, (const float4*)emb_i,
                                                dinv, (ushort4*)g[0], U16, N16);

    for (int layer = 0; layer < 4; ++layer) {
        int threads = N * 64;
        k_layer<<<(threads + B - 1) / B, B, 0, stream>>>(
            (const ushort4*)g[layer], (ushort4*)g[layer + 1], dinv, offs, cnt, csr, N);
    }

    int totalv4 = 2 * U16 + 2 * I16;
    k_final<<<(totalv4 + B - 1) / B, B, 0, stream>>>(
        (const float4*)emb_u, (const float4*)emb_i,
        (const ushort4*)g[1], (const ushort4*)g[2], (const ushort4*)g[3], (const ushort4*)g[4],
        dsq, (float4*)d_out, U16, I16);
}